// Round 8
// baseline (154.813 us; speedup 1.0000x reference)
//
#include <hip/hip_runtime.h>

#define N_NODES 50000
#define N_EDGES 800000
#define D 128
#define NBUCK 196   // ceil(50000/256) buckets of 256 nodes (dst>>8)
#define CAP 4800    // per-bucket capacity; mean 4096, sigma ~64 -> 11 sigma
#define CHUNK 4096  // edges per passA block (16/thread)
#define PA_BLKS ((N_EDGES + CHUNK - 1) / CHUNK)  // 196
#define FB_BLKS 12500                            // N_NODES*64/256
#define WT_BLKS 64                               // 16384/256

typedef __attribute__((ext_vector_type(8))) short short8;
typedef __attribute__((ext_vector_type(4))) float f32x4;

__device__ __forceinline__ unsigned short f2bf(float f) {
    unsigned u = __float_as_uint(f);
    u += 0x7fff + ((u >> 16) & 1);  // RNE
    return (unsigned short)(u >> 16);
}
__device__ __forceinline__ float lo16f(unsigned u) { return __uint_as_float(u << 16); }
__device__ __forceinline__ float hi16f(unsigned u) { return __uint_as_float(u & 0xffff0000u); }

// ---------------------------------------------------------------------------
// K1 (fused): passA buckets edges by dst>>8 into tmp (16 edges/thread, packed
// key = src | dlocal<<16 | bucket<<24); prep converts feature -> packed-bf16
// fb and W -> bf16 n-major Wt. gcur pre-zeroed via memsetAsync.
// ---------------------------------------------------------------------------
__global__ __launch_bounds__(256) void prep_passA(
    const float2* __restrict__ feat2, unsigned* __restrict__ fb,
    const float* __restrict__ W, unsigned short* __restrict__ Wt,
    const int* __restrict__ esrc, const int* __restrict__ edst,
    const float* __restrict__ ew, int* __restrict__ gcur,
    uint2* __restrict__ tmp) {
    __shared__ int lh[NBUCK], lbase[NBUCK], lcur[NBUCK];
    int blk = blockIdx.x, t = threadIdx.x;

    if (blk >= PA_BLKS) {
        int b2 = blk - PA_BLKS;
        if (b2 < FB_BLKS) {
            int i = b2 * 256 + t;
            float2 f = feat2[i];
            fb[i] = (unsigned)f2bf(f.x) | ((unsigned)f2bf(f.y) << 16);
        } else {
            int idx = (b2 - FB_BLKS) * 256 + t;  // 16384 weight elements
            int n = idx >> 7, k = idx & 127;
            Wt[idx] = f2bf(W[k * 128 + n]);
        }
        return;
    }

    // ---- passA ----
    for (int i = t; i < NBUCK; i += 256) lh[i] = 0;
    __syncthreads();
    int e0 = blk * CHUNK;
    unsigned key[16];
    float wv[16];
#pragma unroll
    for (int j = 0; j < 16; ++j) {
        int e = e0 + j * 256 + t;
        if (e < N_EDGES) {
            int src = esrc[e], dd = edst[e];
            key[j] = (unsigned)src | ((unsigned)(dd & 255) << 16) |
                     ((unsigned)(dd >> 8) << 24);
            wv[j] = ew[e];
            atomicAdd(&lh[dd >> 8], 1);
        } else key[j] = 0xff000000u;  // invalid bucket marker
    }
    __syncthreads();
    for (int i = t; i < NBUCK; i += 256) {
        lbase[i] = atomicAdd(&gcur[i], lh[i]);
        lcur[i] = 0;
    }
    __syncthreads();
#pragma unroll
    for (int j = 0; j < 16; ++j) {
        int b = key[j] >> 24;
        if (b < NBUCK) {
            int r = atomicAdd(&lcur[b], 1);
            tmp[(size_t)b * CAP + lbase[b] + r] =
                make_uint2(key[j] & 0x00ffffffu, __float_as_uint(wv[j]));
        }
    }
}

// ---------------------------------------------------------------------------
// K2: one block per bucket -> offsets[] + per-node-sorted sw.
// Bucket-base prefix now via parallel 256-wide scan (was serial t==0 loop).
// ---------------------------------------------------------------------------
__global__ __launch_bounds__(256) void passB(const int* __restrict__ gcur,
                                             const uint2* __restrict__ tmp,
                                             int* __restrict__ offsets,
                                             uint2* __restrict__ sw) {
    __shared__ int hist[256], ps[256];
    __shared__ int sbase, scnt;
    int b = blockIdx.x, t = threadIdx.x;

    // parallel exclusive scan over bucket counts to get this bucket's base
    int gv = (t < NBUCK) ? gcur[t] : 0;
    ps[t] = gv;
    __syncthreads();
    for (int off = 1; off < 256; off <<= 1) {
        int x = (t >= off) ? ps[t - off] : 0;
        __syncthreads();
        ps[t] += x;
        __syncthreads();
    }
    if (t == b) { sbase = ps[t] - gv; scnt = gv; }
    hist[t] = 0;
    __syncthreads();
    int base = sbase, cnt = scnt;
    const uint2* seg = tmp + (size_t)b * CAP;

    for (int i = t; i < cnt; i += 256) atomicAdd(&hist[seg[i].x >> 16], 1);
    __syncthreads();
    int h = hist[t];
    ps[t] = h;
    __syncthreads();
    for (int off = 1; off < 256; off <<= 1) {
        int x = (t >= off) ? ps[t - off] : 0;
        __syncthreads();
        ps[t] += x;
        __syncthreads();
    }
    int o = base + ps[t] - h;
    int node = b * 256 + t;
    if (node < N_NODES) offsets[node] = o;
    if (b == NBUCK - 1 && t == 0) offsets[N_NODES] = N_EDGES;
    __syncthreads();
    hist[t] = o;  // reuse as cursor
    __syncthreads();
    for (int i = t; i < cnt; i += 256) {
        uint2 u = seg[i];
        int pos = atomicAdd(&hist[u.x >> 16], 1);
        sw[pos] = make_uint2(u.x & 0xffffu, u.y);
    }
}

// ---------------------------------------------------------------------------
// K3 (fused): block = 16 nodes, wave aggregates 4. TWO edges per wave-load:
// lanes 0-31 fetch edge A's bf16 row as dwordx2 (4 cols/lane), lanes 32-63
// edge B's. Per-slot (src,w) via one coalesced sw batch load + v_readlane
// (no extra VMEM in the address path). Halves request count, doubles bytes
// in flight per scheduled load. __shfl_xor(32) merges the two half-sums.
// Then blended bf16 rows -> Arows -> 16x128 @ 128x128 MFMA.
// mfma_f32_16x16x32_bf16: A[m=lane&15][k=quad*8+j], B[k][n=lane&15],
// D row=quad*4+reg, col=lane&15 (verified; R2-R6 passed).
// ---------------------------------------------------------------------------
__global__ __launch_bounds__(256) void agg_gemm(const int* __restrict__ offsets,
                                                const uint2* __restrict__ sw,
                                                const unsigned* __restrict__ fb,
                                                const unsigned short* __restrict__ Wt,
                                                float* __restrict__ out) {
    __shared__ unsigned Arows[16][68];
    int wave = threadIdx.x >> 6;
    int lane = threadIdx.x & 63;
    int m = lane & 31;          // uint2 index within a row (cols 4m..4m+3)
    bool low = lane < 32;
    int row0 = blockIdx.x * 16;
    const uint2* fb2 = (const uint2*)fb;

#pragma unroll 1
    for (int i = 0; i < 4; ++i) {
        int n = __builtin_amdgcn_readfirstlane(row0 + wave * 4 + i);
        int b = offsets[n], e2 = offsets[n + 1];
        uint2 sf = fb2[(size_t)n * 32 + m];  // self row (4 cols), independent
        float4 acc = make_float4(0.f, 0.f, 0.f, 0.f);
        int e = b;
        // main: 16 edges per iteration, 8 dwordx2 wave-loads
        for (; e + 16 <= e2; e += 16) {
            uint2 sv = sw[e + (lane & 15)];
#pragma unroll
            for (int j = 0; j < 8; ++j) {
                unsigned sA = __builtin_amdgcn_readlane(sv.x, 2 * j);
                unsigned sB = __builtin_amdgcn_readlane(sv.x, 2 * j + 1);
                unsigned wA = __builtin_amdgcn_readlane(sv.y, 2 * j);
                unsigned wB = __builtin_amdgcn_readlane(sv.y, 2 * j + 1);
                unsigned src = low ? sA : sB;
                float w = __uint_as_float(low ? wA : wB);
                uint2 dv = fb2[(size_t)src * 32 + m];
                acc.x += w * lo16f(dv.x);
                acc.y += w * hi16f(dv.x);
                acc.z += w * lo16f(dv.y);
                acc.w += w * hi16f(dv.y);
            }
        }
        // tail: up to 15 edges, 2 per slot, odd edge masked with w=0
        if (e < e2) {
            int cnt = e2 - e;
            uint2 sv = sw[e + ((lane & 15) < cnt ? (lane & 15) : cnt - 1)];
#pragma unroll 1
            for (int j = 0; 2 * j < cnt; ++j) {
                unsigned sA = __builtin_amdgcn_readlane(sv.x, 2 * j);
                unsigned wA = __builtin_amdgcn_readlane(sv.y, 2 * j);
                bool hasB = (2 * j + 1) < cnt;
                unsigned sB = hasB ? __builtin_amdgcn_readlane(sv.x, 2 * j + 1) : sA;
                unsigned wB = hasB ? __builtin_amdgcn_readlane(sv.y, 2 * j + 1) : 0u;
                unsigned src = low ? sA : sB;
                float w = __uint_as_float(low ? wA : wB);
                uint2 dv = fb2[(size_t)src * 32 + m];
                acc.x += w * lo16f(dv.x);
                acc.y += w * hi16f(dv.x);
                acc.z += w * lo16f(dv.y);
                acc.w += w * hi16f(dv.y);
            }
        }
        // merge the two half-wave partial sums (lane <-> lane^32)
        acc.x += __shfl_xor(acc.x, 32);
        acc.y += __shfl_xor(acc.y, 32);
        acc.z += __shfl_xor(acc.z, 32);
        acc.w += __shfl_xor(acc.w, 32);
        if (low) {
            float r0 = 0.5f * (acc.x + lo16f(sf.x));
            float r1 = 0.5f * (acc.y + hi16f(sf.x));
            float r2 = 0.5f * (acc.z + lo16f(sf.y));
            float r3 = 0.5f * (acc.w + hi16f(sf.y));
            int r = wave * 4 + i;
            Arows[r][2 * m]     = (unsigned)f2bf(r0) | ((unsigned)f2bf(r1) << 16);
            Arows[r][2 * m + 1] = (unsigned)f2bf(r2) | ((unsigned)f2bf(r3) << 16);
        }
    }
    __syncthreads();

    int quad = lane >> 4;
    int col  = lane & 15;
    short8 a[4];
#pragma unroll
    for (int kk = 0; kk < 4; ++kk)
        a[kk] = *reinterpret_cast<const short8*>(&Arows[col][kk * 16 + quad * 4]);

#pragma unroll
    for (int ii = 0; ii < 2; ++ii) {
        int n0 = wave * 2 + ii;
        const short8* bp = reinterpret_cast<const short8*>(Wt) + ((n0 * 16 + col) * 16 + quad);
        f32x4 acc = {0.f, 0.f, 0.f, 0.f};
        acc = __builtin_amdgcn_mfma_f32_16x16x32_bf16(a[0], bp[0],  acc, 0, 0, 0);
        acc = __builtin_amdgcn_mfma_f32_16x16x32_bf16(a[1], bp[4],  acc, 0, 0, 0);
        acc = __builtin_amdgcn_mfma_f32_16x16x32_bf16(a[2], bp[8],  acc, 0, 0, 0);
        acc = __builtin_amdgcn_mfma_f32_16x16x32_bf16(a[3], bp[12], acc, 0, 0, 0);
#pragma unroll
        for (int rr = 0; rr < 4; ++rr)
            out[(size_t)(row0 + quad * 4 + rr) * D + n0 * 16 + col] = acc[rr];
    }
}

// ---------------------------------------------------------------------------
extern "C" void kernel_launch(void* const* d_in, const int* in_sizes, int n_in,
                              void* d_out, int out_size, void* d_ws, size_t ws_size,
                              hipStream_t stream) {
    const float* feat = (const float*)d_in[0];
    const int*   esrc = (const int*)d_in[1];
    const int*   edst = (const int*)d_in[2];
    const float* ew   = (const float*)d_in[3];
    const float* W    = (const float*)d_in[4];
    float*       out  = (float*)d_out;

    char* ws = (char*)d_ws;
    uint2*          sw      = (uint2*)(ws + 0);                   //  6,400,000
    unsigned*       fb      = (unsigned*)(ws + 6400000);          // 12,800,000
    int*            offsets = (int*)(ws + 19200000);              //    200,004
    unsigned short* Wt      = (unsigned short*)(ws + 19400064);   //     32,768
    int*            gcur    = (int*)(ws + 19432832);              //        784
    // tmp (7.53 MB) aliases d_out, dead until agg_gemm overwrites it.
    uint2* tmp = (uint2*)d_out;

    hipMemsetAsync(gcur, 0, NBUCK * sizeof(int), stream);
    prep_passA<<<PA_BLKS + FB_BLKS + WT_BLKS, 256, 0, stream>>>(
        (const float2*)feat, fb, W, Wt, esrc, edst, ew, gcur, tmp);
    passB<<<NBUCK, 256, 0, stream>>>(gcur, tmp, offsets, sw);
    agg_gemm<<<N_NODES / 16, 256, 0, stream>>>(offsets, sw, fb, Wt, out);
}

// Round 9
// 149.928 us; speedup vs baseline: 1.0326x; 1.0326x over previous
//
#include <hip/hip_runtime.h>

#define N_NODES 50000
#define N_EDGES 800000
#define D 128
#define NBUCK 196   // ceil(50000/256) buckets of 256 nodes (dst>>8)
#define CAP 4800    // per-bucket capacity; mean 4096, sigma ~64 -> 11 sigma
#define CHUNK 4096  // edges per passA block (16/thread)
#define PA_BLKS ((N_EDGES + CHUNK - 1) / CHUNK)  // 196
#define FB_BLKS 12500                            // N_NODES*64/256
#define WT_BLKS 64                               // 16384/256

typedef __attribute__((ext_vector_type(8))) short short8;
typedef __attribute__((ext_vector_type(4))) float f32x4;

__device__ __forceinline__ unsigned short f2bf(float f) {
    unsigned u = __float_as_uint(f);
    u += 0x7fff + ((u >> 16) & 1);  // RNE
    return (unsigned short)(u >> 16);
}
__device__ __forceinline__ float lo16f(unsigned u) { return __uint_as_float(u << 16); }
__device__ __forceinline__ float hi16f(unsigned u) { return __uint_as_float(u & 0xffff0000u); }

// ---------------------------------------------------------------------------
// K1 (fused): passA buckets edges by dst>>8 into tmp (16 edges/thread, packed
// key = src | dlocal<<16 | bucket<<24); prep converts feature -> packed-bf16
// fb and W -> bf16 n-major Wt. gcur pre-zeroed via memsetAsync.
// ---------------------------------------------------------------------------
__global__ __launch_bounds__(256) void prep_passA(
    const float2* __restrict__ feat2, unsigned* __restrict__ fb,
    const float* __restrict__ W, unsigned short* __restrict__ Wt,
    const int* __restrict__ esrc, const int* __restrict__ edst,
    const float* __restrict__ ew, int* __restrict__ gcur,
    uint2* __restrict__ tmp) {
    __shared__ int lh[NBUCK], lbase[NBUCK], lcur[NBUCK];
    int blk = blockIdx.x, t = threadIdx.x;

    if (blk >= PA_BLKS) {
        int b2 = blk - PA_BLKS;
        if (b2 < FB_BLKS) {
            int i = b2 * 256 + t;
            float2 f = feat2[i];
            fb[i] = (unsigned)f2bf(f.x) | ((unsigned)f2bf(f.y) << 16);
        } else {
            int idx = (b2 - FB_BLKS) * 256 + t;  // 16384 weight elements
            int n = idx >> 7, k = idx & 127;
            Wt[idx] = f2bf(W[k * 128 + n]);
        }
        return;
    }

    // ---- passA ----
    for (int i = t; i < NBUCK; i += 256) lh[i] = 0;
    __syncthreads();
    int e0 = blk * CHUNK;
    unsigned key[16];
    float wv[16];
#pragma unroll
    for (int j = 0; j < 16; ++j) {
        int e = e0 + j * 256 + t;
        if (e < N_EDGES) {
            int src = esrc[e], dd = edst[e];
            key[j] = (unsigned)src | ((unsigned)(dd & 255) << 16) |
                     ((unsigned)(dd >> 8) << 24);
            wv[j] = ew[e];
            atomicAdd(&lh[dd >> 8], 1);
        } else key[j] = 0xff000000u;  // invalid bucket marker
    }
    __syncthreads();
    for (int i = t; i < NBUCK; i += 256) {
        lbase[i] = atomicAdd(&gcur[i], lh[i]);
        lcur[i] = 0;
    }
    __syncthreads();
#pragma unroll
    for (int j = 0; j < 16; ++j) {
        int b = key[j] >> 24;
        if (b < NBUCK) {
            int r = atomicAdd(&lcur[b], 1);
            tmp[(size_t)b * CAP + lbase[b] + r] =
                make_uint2(key[j] & 0x00ffffffu, __float_as_uint(wv[j]));
        }
    }
}

// ---------------------------------------------------------------------------
// K2: one block per bucket -> offsets[] + per-node-sorted sw.
// ---------------------------------------------------------------------------
__global__ __launch_bounds__(256) void passB(const int* __restrict__ gcur,
                                             const uint2* __restrict__ tmp,
                                             int* __restrict__ offsets,
                                             uint2* __restrict__ sw) {
    __shared__ int hist[256], ps[256];
    __shared__ int sbase, scnt;
    int b = blockIdx.x, t = threadIdx.x;

    // parallel exclusive scan over bucket counts to get this bucket's base
    int gv = (t < NBUCK) ? gcur[t] : 0;
    ps[t] = gv;
    __syncthreads();
    for (int off = 1; off < 256; off <<= 1) {
        int x = (t >= off) ? ps[t - off] : 0;
        __syncthreads();
        ps[t] += x;
        __syncthreads();
    }
    if (t == b) { sbase = ps[t] - gv; scnt = gv; }
    hist[t] = 0;
    __syncthreads();
    int base = sbase, cnt = scnt;
    const uint2* seg = tmp + (size_t)b * CAP;

    for (int i = t; i < cnt; i += 256) atomicAdd(&hist[seg[i].x >> 16], 1);
    __syncthreads();
    int h = hist[t];
    ps[t] = h;
    __syncthreads();
    for (int off = 1; off < 256; off <<= 1) {
        int x = (t >= off) ? ps[t - off] : 0;
        __syncthreads();
        ps[t] += x;
        __syncthreads();
    }
    int o = base + ps[t] - h;
    int node = b * 256 + t;
    if (node < N_NODES) offsets[node] = o;
    if (b == NBUCK - 1 && t == 0) offsets[N_NODES] = N_EDGES;
    __syncthreads();
    hist[t] = o;  // reuse as cursor
    __syncthreads();
    for (int i = t; i < cnt; i += 256) {
        uint2 u = seg[i];
        int pos = atomicAdd(&hist[u.x >> 16], 1);
        sw[pos] = make_uint2(u.x & 0xffffu, u.y);
    }
}

// ---------------------------------------------------------------------------
// K3 (fused): block = 16 nodes, wave aggregates 4. __launch_bounds__(256,2)
// lifts the VGPR cap to 256 so a full 16-edge batch (p[16] sw entries,
// u[16] gathered rows) PLUS the next batch's pn[16] stay live (~110 VGPR)
// -> ~32 loads in flight per wave instead of the 2-4 the register-minimizing
// scheduler produced at VGPR=32 (R5-R7 all pinned at 44-49 us).
// Tail batch is clamp-padded with weights zeroed -> all loops fixed-trip.
// Then blended bf16 rows -> Arows -> 16x128 @ 128x128 MFMA.
// mfma_f32_16x16x32_bf16: A[m=lane&15][k=quad*8+j], B[k][n=lane&15],
// D row=quad*4+reg, col=lane&15 (verified; R2-R7 passed).
// ---------------------------------------------------------------------------
__global__ __launch_bounds__(256, 2) void agg_gemm(const int* __restrict__ offsets,
                                                   const uint2* __restrict__ sw,
                                                   const unsigned* __restrict__ fb,
                                                   const unsigned short* __restrict__ Wt,
                                                   float* __restrict__ out) {
    __shared__ unsigned Arows[16][68];
    int wave = threadIdx.x >> 6;
    int lane = threadIdx.x & 63;
    int row0 = blockIdx.x * 16;

#pragma unroll 1
    for (int i = 0; i < 4; ++i) {
        int n = __builtin_amdgcn_readfirstlane(row0 + wave * 4 + i);
        int b = offsets[n], e2 = offsets[n + 1];
        unsigned us = fb[(size_t)n * 64 + lane];  // self row
        float ax = 0.f, ay = 0.f;
        int e = b;
        int nfull = (e2 - b) >> 4;

        uint2 p[16];
        {   // preload first batch (clamped; OOB-safe: sw is followed by fb in ws)
            int rem = e2 - e;
#pragma unroll
            for (int j = 0; j < 16; ++j) {
                int idx = (j < rem) ? j : (rem > 0 ? rem - 1 : 0);
                p[j] = sw[e + idx];
            }
        }
#pragma unroll 1
        for (int t = 0; t < nfull; ++t) {
            unsigned u[16];
#pragma unroll
            for (int j = 0; j < 16; ++j) u[j] = fb[(size_t)p[j].x * 64 + lane];
            // prefetch next batch while the 16 gathers are in flight
            int en = e + 16;
            int rem = e2 - en;
            uint2 pn[16];
#pragma unroll
            for (int j = 0; j < 16; ++j) {
                int idx = (j < rem) ? j : (rem > 0 ? rem - 1 : 0);
                pn[j] = sw[en + idx];
            }
#pragma unroll
            for (int j = 0; j < 16; ++j) {
                float w = __uint_as_float(p[j].y);
                ax += w * lo16f(u[j]);
                ay += w * hi16f(u[j]);
            }
#pragma unroll
            for (int j = 0; j < 16; ++j) p[j] = pn[j];
            e = en;
        }
        int rem = e2 - e;
        if (rem > 0) {  // tail: p already holds the clamp-padded batch
            unsigned u[16];
#pragma unroll
            for (int j = 0; j < 16; ++j) u[j] = fb[(size_t)p[j].x * 64 + lane];
#pragma unroll
            for (int j = 0; j < 16; ++j) {
                float w = (j < rem) ? __uint_as_float(p[j].y) : 0.f;
                ax += w * lo16f(u[j]);
                ay += w * hi16f(u[j]);
            }
        }
        float rx = 0.5f * (ax + lo16f(us));
        float ry = 0.5f * (ay + hi16f(us));
        Arows[wave * 4 + i][lane] = (unsigned)f2bf(rx) | ((unsigned)f2bf(ry) << 16);
    }
    __syncthreads();

    int quad = lane >> 4;
    int col  = lane & 15;
    short8 a[4];
#pragma unroll
    for (int kk = 0; kk < 4; ++kk)
        a[kk] = *reinterpret_cast<const short8*>(&Arows[col][kk * 16 + quad * 4]);

#pragma unroll
    for (int ii = 0; ii < 2; ++ii) {
        int n0 = wave * 2 + ii;
        const short8* bp = reinterpret_cast<const short8*>(Wt) + ((n0 * 16 + col) * 16 + quad);
        f32x4 acc = {0.f, 0.f, 0.f, 0.f};
        acc = __builtin_amdgcn_mfma_f32_16x16x32_bf16(a[0], bp[0],  acc, 0, 0, 0);
        acc = __builtin_amdgcn_mfma_f32_16x16x32_bf16(a[1], bp[4],  acc, 0, 0, 0);
        acc = __builtin_amdgcn_mfma_f32_16x16x32_bf16(a[2], bp[8],  acc, 0, 0, 0);
        acc = __builtin_amdgcn_mfma_f32_16x16x32_bf16(a[3], bp[12], acc, 0, 0, 0);
#pragma unroll
        for (int rr = 0; rr < 4; ++rr)
            out[(size_t)(row0 + quad * 4 + rr) * D + n0 * 16 + col] = acc[rr];
    }
}

// ---------------------------------------------------------------------------
extern "C" void kernel_launch(void* const* d_in, const int* in_sizes, int n_in,
                              void* d_out, int out_size, void* d_ws, size_t ws_size,
                              hipStream_t stream) {
    const float* feat = (const float*)d_in[0];
    const int*   esrc = (const int*)d_in[1];
    const int*   edst = (const int*)d_in[2];
    const float* ew   = (const float*)d_in[3];
    const float* W    = (const float*)d_in[4];
    float*       out  = (float*)d_out;

    char* ws = (char*)d_ws;
    uint2*          sw      = (uint2*)(ws + 0);                   //  6,400,000
    unsigned*       fb      = (unsigned*)(ws + 6400000);          // 12,800,000
    int*            offsets = (int*)(ws + 19200000);              //    200,004
    unsigned short* Wt      = (unsigned short*)(ws + 19400064);   //     32,768
    int*            gcur    = (int*)(ws + 19432832);              //        784
    // tmp (7.53 MB) aliases d_out, dead until agg_gemm overwrites it.
    uint2* tmp = (uint2*)d_out;

    hipMemsetAsync(gcur, 0, NBUCK * sizeof(int), stream);
    prep_passA<<<PA_BLKS + FB_BLKS + WT_BLKS, 256, 0, stream>>>(
        (const float2*)feat, fb, W, Wt, esrc, edst, ew, gcur, tmp);
    passB<<<NBUCK, 256, 0, stream>>>(gcur, tmp, offsets, sw);
    agg_gemm<<<N_NODES / 16, 256, 0, stream>>>(offsets, sw, fb, Wt, out);
}